// Round 1
// baseline (646.016 us; speedup 1.0000x reference)
//
#include <hip/hip_runtime.h>
#include <hip/hip_bf16.h>
#include <math.h>

// ---------------- problem constants ----------------
#define T_TOK 2048
#define H_DIM 512
#define E_NUM 16
#define TOPK  2
#define I_DIM 2048
#define IS_DIM 1024
#define NROWS (T_TOK * TOPK)   // 4096 routed (token,expert) rows
#define LDA 40                 // LDS row stride in bf16 elems (80B) -> 2-way-free banks

typedef __attribute__((ext_vector_type(8))) short bf16x8;
typedef __attribute__((ext_vector_type(4))) float f32x4;

static __device__ __forceinline__ unsigned short f2bf(float f) {
  unsigned int u = __float_as_uint(f);
  unsigned int r = (u + 0x7fffu + ((u >> 16) & 1u)) >> 16;   // RNE
  return (unsigned short)r;
}

static __device__ __forceinline__ bf16x8 pack8(float4 a, float4 b) {
  bf16x8 v;
  v[0] = (short)f2bf(a.x); v[1] = (short)f2bf(a.y);
  v[2] = (short)f2bf(a.z); v[3] = (short)f2bf(a.w);
  v[4] = (short)f2bf(b.x); v[5] = (short)f2bf(b.y);
  v[6] = (short)f2bf(b.z); v[7] = (short)f2bf(b.w);
  return v;
}

// ---------------- 1) gate: logits -> softmax -> top2 -> counts ----------------
__global__ __launch_bounds__(64) void gate_kernel(
    const float* __restrict__ x, const float* __restrict__ gw,
    int* __restrict__ topk_idx, float* __restrict__ topk_w, int* __restrict__ counts)
{
  int t = blockIdx.x;
  int lane = threadIdx.x;
  __shared__ float xs[H_DIM];
  __shared__ float lg[E_NUM];
  const float4* xr = (const float4*)(x + (size_t)t * H_DIM);
  ((float4*)xs)[lane] = xr[lane];
  ((float4*)xs)[lane + 64] = xr[lane + 64];
  __syncthreads();
  if (lane < E_NUM) {
    const float* w = gw + (size_t)lane * H_DIM;
    float acc = 0.f;
    #pragma unroll 8
    for (int h = 0; h < H_DIM; h++) acc += xs[h] * w[h];
    lg[lane] = acc;
  }
  __syncthreads();
  if (lane == 0) {
    float mx = lg[0];
    #pragma unroll
    for (int e = 1; e < E_NUM; e++) mx = fmaxf(mx, lg[e]);
    float sc[E_NUM];
    float sum = 0.f;
    #pragma unroll
    for (int e = 0; e < E_NUM; e++) { sc[e] = expf(lg[e] - mx); sum += sc[e]; }
    float inv = 1.f / sum;
    float m1 = -1.f, m2 = -1.f; int i1 = 0, i2 = 0;
    #pragma unroll
    for (int e = 0; e < E_NUM; e++) {
      float s = sc[e] * inv;
      if (s > m1)      { m2 = m1; i2 = i1; m1 = s; i1 = e; }
      else if (s > m2) { m2 = s; i2 = e; }
    }
    topk_idx[t * 2] = i1; topk_idx[t * 2 + 1] = i2;
    topk_w[t * 2] = m1;  topk_w[t * 2 + 1] = m2;
    atomicAdd(&counts[i1], 1);
    atomicAdd(&counts[i2], 1);
  }
}

// ---------------- 2) exclusive scan over 16 counts ----------------
__global__ void offsets_kernel(const int* __restrict__ counts,
                               int* __restrict__ offsets, int* __restrict__ cursor)
{
  if (threadIdx.x == 0) {
    int acc = 0;
    #pragma unroll
    for (int e = 0; e < E_NUM; e++) { offsets[e] = acc; acc += counts[e]; }
    offsets[E_NUM] = acc;
  }
  if (threadIdx.x < E_NUM) cursor[threadIdx.x] = 0;
}

// ---------------- 3) scatter tokens into per-expert lists ----------------
__global__ __launch_bounds__(256) void scatter_kernel(
    const int* __restrict__ topk_idx, const float* __restrict__ topk_w,
    const int* __restrict__ offsets, int* __restrict__ cursor,
    int* __restrict__ row_token, float* __restrict__ row_w)
{
  int t = blockIdx.x * 256 + threadIdx.x;
  if (t >= T_TOK) return;
  #pragma unroll
  for (int k = 0; k < TOPK; k++) {
    int e = topk_idx[t * 2 + k];
    int pos = atomicAdd(&cursor[e], 1);
    int row = offsets[e] + pos;
    row_token[row] = t;
    row_w[row] = topk_w[t * 2 + k];
  }
}

// ---------------- 4) grouped GU GEMM: inter = silu(X*Wg^T) .* (X*Wu^T) ----------------
// grid.x = nE*maxrt (row tiles of 64 rows), grid.y = Idim/64 (col tiles). block=256.
__global__ __launch_bounds__(256) void gu_kernel(
    const float* __restrict__ x,
    const float* __restrict__ wg_base, const float* __restrict__ wu_base,
    unsigned short* __restrict__ inter,
    const int* __restrict__ row_token,   // null -> identity rows
    const int* __restrict__ counts,      // null -> cnt = total_rows
    const int* __restrict__ offsets,     // null -> base = 0
    int Idim, int total_rows, int maxrt)
{
  int e  = blockIdx.x / maxrt;
  int rt = blockIdx.x % maxrt;
  int cnt = counts ? counts[e] : total_rows;
  int n0 = rt * 64;
  if (n0 >= cnt) return;
  int base = offsets ? offsets[e] : 0;
  int col0 = blockIdx.y * 64;
  const float* wg = wg_base + (size_t)e * Idim * H_DIM;
  const float* wu = wu_base + (size_t)e * Idim * H_DIM;

  __shared__ __align__(16) unsigned short As[64 * LDA];
  __shared__ __align__(16) unsigned short Bgs[64 * LDA];
  __shared__ __align__(16) unsigned short Bus[64 * LDA];
  __shared__ int toks[64];

  int tid = threadIdx.x;
  if (tid < 64) {
    int r = n0 + tid;
    toks[tid] = (r < cnt) ? (row_token ? row_token[base + r] : (base + r)) : -1;
  }
  __syncthreads();

  int wid = tid >> 6, lane = tid & 63;
  int wr = (wid >> 1) * 32, wc = (wid & 1) * 32;
  int fr = lane & 15, fk = (lane >> 4) * 8;

  int arow = tid >> 2;
  int acol = (tid & 3) * 8;
  int mytok = toks[arow];
  const float* asrc  = (mytok >= 0) ? (x + (size_t)mytok * H_DIM + acol) : nullptr;
  const float* bsrcg = wg + (size_t)(col0 + arow) * H_DIM + acol;
  const float* bsrcu = wu + (size_t)(col0 + arow) * H_DIM + acol;

  f32x4 accg[2][2] = {};
  f32x4 accu[2][2] = {};

  for (int k0 = 0; k0 < H_DIM; k0 += 32) {
    bf16x8 av = {};
    if (asrc) {
      float4 f0 = *(const float4*)(asrc + k0);
      float4 f1 = *(const float4*)(asrc + k0 + 4);
      av = pack8(f0, f1);
    }
    float4 g0 = *(const float4*)(bsrcg + k0);
    float4 g1 = *(const float4*)(bsrcg + k0 + 4);
    float4 u0 = *(const float4*)(bsrcu + k0);
    float4 u1 = *(const float4*)(bsrcu + k0 + 4);
    bf16x8 bgv = pack8(g0, g1);
    bf16x8 buv = pack8(u0, u1);
    *(bf16x8*)&As[arow * LDA + acol]  = av;
    *(bf16x8*)&Bgs[arow * LDA + acol] = bgv;
    *(bf16x8*)&Bus[arow * LDA + acol] = buv;
    __syncthreads();

    bf16x8 a0  = *(const bf16x8*)&As[(wr + fr) * LDA + fk];
    bf16x8 a1  = *(const bf16x8*)&As[(wr + 16 + fr) * LDA + fk];
    bf16x8 bg0 = *(const bf16x8*)&Bgs[(wc + fr) * LDA + fk];
    bf16x8 bg1 = *(const bf16x8*)&Bgs[(wc + 16 + fr) * LDA + fk];
    bf16x8 bu0 = *(const bf16x8*)&Bus[(wc + fr) * LDA + fk];
    bf16x8 bu1 = *(const bf16x8*)&Bus[(wc + 16 + fr) * LDA + fk];

    accg[0][0] = __builtin_amdgcn_mfma_f32_16x16x32_bf16(a0, bg0, accg[0][0], 0, 0, 0);
    accg[1][0] = __builtin_amdgcn_mfma_f32_16x16x32_bf16(a1, bg0, accg[1][0], 0, 0, 0);
    accg[0][1] = __builtin_amdgcn_mfma_f32_16x16x32_bf16(a0, bg1, accg[0][1], 0, 0, 0);
    accg[1][1] = __builtin_amdgcn_mfma_f32_16x16x32_bf16(a1, bg1, accg[1][1], 0, 0, 0);
    accu[0][0] = __builtin_amdgcn_mfma_f32_16x16x32_bf16(a0, bu0, accu[0][0], 0, 0, 0);
    accu[1][0] = __builtin_amdgcn_mfma_f32_16x16x32_bf16(a1, bu0, accu[1][0], 0, 0, 0);
    accu[0][1] = __builtin_amdgcn_mfma_f32_16x16x32_bf16(a0, bu1, accu[0][1], 0, 0, 0);
    accu[1][1] = __builtin_amdgcn_mfma_f32_16x16x32_bf16(a1, bu1, accu[1][1], 0, 0, 0);
    __syncthreads();
  }

  #pragma unroll
  for (int mb = 0; mb < 2; mb++) {
    #pragma unroll
    for (int nb = 0; nb < 2; nb++) {
      int col = col0 + wc + nb * 16 + fr;
      #pragma unroll
      for (int j = 0; j < 4; j++) {
        int m = wr + mb * 16 + ((lane >> 4) << 2) + j;
        if (n0 + m < cnt) {
          float g = accg[mb][nb][j];
          float u = accu[mb][nb][j];
          float s = (g / (1.f + expf(-g))) * u;   // silu(g)*u
          inter[(size_t)(base + n0 + m) * Idim + col] = f2bf(s);
        }
      }
    }
  }
}

// ---------------- 5) down GEMM: out(+)= (inter * Wd^T) [* weight] ----------------
// routed (row_w != null): atomicAdd weighted into out[token]; shared: plain store.
__global__ __launch_bounds__(256) void down_kernel(
    const unsigned short* __restrict__ inter,
    const float* __restrict__ wd_base,
    float* __restrict__ outp,
    const int* __restrict__ row_token,   // null -> identity rows
    const float* __restrict__ row_w,     // null -> store (shared expert)
    const int* __restrict__ counts, const int* __restrict__ offsets,
    int Kdim, int total_rows, int maxrt)
{
  int e  = blockIdx.x / maxrt;
  int rt = blockIdx.x % maxrt;
  int cnt = counts ? counts[e] : total_rows;
  int n0 = rt * 64;
  if (n0 >= cnt) return;
  int base = offsets ? offsets[e] : 0;
  int col0 = blockIdx.y * 64;
  const float* wd = wd_base + (size_t)e * H_DIM * Kdim;

  __shared__ __align__(16) unsigned short As[64 * LDA];
  __shared__ __align__(16) unsigned short Bs[64 * LDA];
  __shared__ int   toks[64];
  __shared__ float rws[64];

  int tid = threadIdx.x;
  if (tid < 64) {
    int r = n0 + tid;
    if (r < cnt) {
      int row = base + r;
      toks[tid] = row_token ? row_token[row] : row;
      rws[tid]  = row_w ? row_w[row] : 1.f;
    } else { toks[tid] = 0; rws[tid] = 0.f; }
  }
  __syncthreads();

  int wid = tid >> 6, lane = tid & 63;
  int wr = (wid >> 1) * 32, wc = (wid & 1) * 32;
  int fr = lane & 15, fk = (lane >> 4) * 8;

  int arow = tid >> 2;
  int acol = (tid & 3) * 8;
  bool avalid = (n0 + arow) < cnt;
  const unsigned short* asrc = avalid ? (inter + (size_t)(base + n0 + arow) * Kdim + acol) : nullptr;
  const float* bsrc = wd + (size_t)(col0 + arow) * Kdim + acol;

  f32x4 acc[2][2] = {};

  for (int k0 = 0; k0 < Kdim; k0 += 32) {
    bf16x8 av = {};
    if (asrc) av = *(const bf16x8*)(asrc + k0);
    float4 b0 = *(const float4*)(bsrc + k0);
    float4 b1 = *(const float4*)(bsrc + k0 + 4);
    bf16x8 bv = pack8(b0, b1);
    *(bf16x8*)&As[arow * LDA + acol] = av;
    *(bf16x8*)&Bs[arow * LDA + acol] = bv;
    __syncthreads();

    bf16x8 a0 = *(const bf16x8*)&As[(wr + fr) * LDA + fk];
    bf16x8 a1 = *(const bf16x8*)&As[(wr + 16 + fr) * LDA + fk];
    bf16x8 b0f = *(const bf16x8*)&Bs[(wc + fr) * LDA + fk];
    bf16x8 b1f = *(const bf16x8*)&Bs[(wc + 16 + fr) * LDA + fk];

    acc[0][0] = __builtin_amdgcn_mfma_f32_16x16x32_bf16(a0, b0f, acc[0][0], 0, 0, 0);
    acc[1][0] = __builtin_amdgcn_mfma_f32_16x16x32_bf16(a1, b0f, acc[1][0], 0, 0, 0);
    acc[0][1] = __builtin_amdgcn_mfma_f32_16x16x32_bf16(a0, b1f, acc[0][1], 0, 0, 0);
    acc[1][1] = __builtin_amdgcn_mfma_f32_16x16x32_bf16(a1, b1f, acc[1][1], 0, 0, 0);
    __syncthreads();
  }

  #pragma unroll
  for (int mb = 0; mb < 2; mb++) {
    #pragma unroll
    for (int nb = 0; nb < 2; nb++) {
      int col = col0 + wc + nb * 16 + fr;
      #pragma unroll
      for (int j = 0; j < 4; j++) {
        int m = wr + mb * 16 + ((lane >> 4) << 2) + j;
        if (n0 + m < cnt) {
          int tk = toks[m];
          float v = acc[mb][nb][j];
          if (row_w) atomicAdd(&outp[(size_t)tk * H_DIM + col], v * rws[m]);
          else       outp[(size_t)tk * H_DIM + col] = v;
        }
      }
    }
  }
}

// ---------------- launch ----------------
extern "C" void kernel_launch(void* const* d_in, const int* in_sizes, int n_in,
                              void* d_out, int out_size, void* d_ws, size_t ws_size,
                              hipStream_t stream) {
  const float* x       = (const float*)d_in[0];
  const float* gate_w  = (const float*)d_in[1];
  const float* w_gate  = (const float*)d_in[2];
  const float* w_up    = (const float*)d_in[3];
  const float* w_down  = (const float*)d_in[4];
  const float* sw_gate = (const float*)d_in[5];
  const float* sw_up   = (const float*)d_in[6];
  const float* sw_down = (const float*)d_in[7];
  float* out = (float*)d_out;

  char* ws = (char*)d_ws;
  int*   counts    = (int*)ws;                    // 16 ints
  int*   cursor    = (int*)(ws + 64);             // 16 ints
  int*   offsets   = (int*)(ws + 128);            // 17 ints
  int*   topk_idx  = (int*)(ws + 256);            // 4096 ints
  float* topk_w    = (float*)(ws + 256 + 16384);  // 4096 f32
  int*   row_token = (int*)(ws + 256 + 32768);    // 4096 ints
  float* row_w     = (float*)(ws + 256 + 49152);  // 4096 f32
  unsigned short* inter_r = (unsigned short*)(ws + 65792);              // 4096x2048 bf16 = 16 MiB
  unsigned short* inter_s = (unsigned short*)(ws + 65792 + 16777216);   // 2048x1024 bf16 = 4 MiB

  hipMemsetAsync(counts, 0, 64, stream);
  gate_kernel<<<T_TOK, 64, 0, stream>>>(x, gate_w, topk_idx, topk_w, counts);
  offsets_kernel<<<1, 64, 0, stream>>>(counts, offsets, cursor);
  scatter_kernel<<<(T_TOK + 255) / 256, 256, 0, stream>>>(topk_idx, topk_w, offsets, cursor,
                                                          row_token, row_w);
  // routed GU: 4096 rows grouped by expert; worst-case 32 row-tiles/expert
  gu_kernel<<<dim3(E_NUM * 32, I_DIM / 64), 256, 0, stream>>>(
      x, w_gate, w_up, inter_r, row_token, counts, offsets, I_DIM, NROWS, 32);
  // shared GU: dense 2048 rows
  gu_kernel<<<dim3(32, IS_DIM / 64), 256, 0, stream>>>(
      x, sw_gate, sw_up, inter_s, nullptr, nullptr, nullptr, IS_DIM, T_TOK, 32);
  // shared down first (plain stores initialize out fully)
  down_kernel<<<dim3(32, H_DIM / 64), 256, 0, stream>>>(
      inter_s, sw_down, out, nullptr, nullptr, nullptr, nullptr, IS_DIM, T_TOK, 32);
  // routed down: weighted atomic accumulation into out
  down_kernel<<<dim3(E_NUM * 32, H_DIM / 64), 256, 0, stream>>>(
      inter_r, w_down, out, row_token, row_w, counts, offsets, I_DIM, NROWS, 32);
}

// Round 2
// 516.825 us; speedup vs baseline: 1.2500x; 1.2500x over previous
//
#include <hip/hip_runtime.h>
#include <hip/hip_bf16.h>
#include <math.h>

// ---------------- problem constants ----------------
#define T_TOK 2048
#define H_DIM 512
#define E_NUM 16
#define TOPK  2
#define I_DIM 2048
#define IS_DIM 1024
#define NROWS (T_TOK * TOPK)   // 4096 routed (token,expert) rows

typedef __attribute__((ext_vector_type(8))) short bf16x8;
typedef __attribute__((ext_vector_type(4))) float f32x4;
typedef unsigned short ushort_t;

static __device__ __forceinline__ unsigned short f2bf(float f) {
  unsigned int u = __float_as_uint(f);
  unsigned int r = (u + 0x7fffu + ((u >> 16) & 1u)) >> 16;   // RNE
  return (unsigned short)r;
}

static __device__ __forceinline__ bf16x8 pack8(float4 a, float4 b) {
  bf16x8 v;
  v[0] = (short)f2bf(a.x); v[1] = (short)f2bf(a.y);
  v[2] = (short)f2bf(a.z); v[3] = (short)f2bf(a.w);
  v[4] = (short)f2bf(b.x); v[5] = (short)f2bf(b.y);
  v[6] = (short)f2bf(b.z); v[7] = (short)f2bf(b.w);
  return v;
}

// async global->LDS, 16B per lane. LDS dest: wave-uniform base + lane*16.
static __device__ __forceinline__ void gload_lds16(const void* g, void* l) {
  __builtin_amdgcn_global_load_lds(
      (const __attribute__((address_space(1))) unsigned int*)g,
      (__attribute__((address_space(3))) unsigned int*)l, 16, 0, 0);
}

// ---------------- 0) fp32 -> bf16 conversion (grid-stride, 8 elems/thread/iter) ----
__global__ __launch_bounds__(256) void conv_kernel(const float* __restrict__ s,
                                                   ushort_t* __restrict__ d, int n8) {
  int i = blockIdx.x * 256 + threadIdx.x;
  int stride = gridDim.x * 256;
  for (; i < n8; i += stride) {
    float4 f0 = ((const float4*)s)[(size_t)i * 2];
    float4 f1 = ((const float4*)s)[(size_t)i * 2 + 1];
    ((bf16x8*)d)[i] = pack8(f0, f1);
  }
}

// ---------------- 1) gate: logits -> softmax -> top2 -> counts ----------------
__global__ __launch_bounds__(64) void gate_kernel(
    const float* __restrict__ x, const float* __restrict__ gw,
    int* __restrict__ topk_idx, float* __restrict__ topk_w, int* __restrict__ counts)
{
  int t = blockIdx.x;
  int lane = threadIdx.x;
  __shared__ float xs[H_DIM];
  __shared__ float lg[E_NUM];
  const float4* xr = (const float4*)(x + (size_t)t * H_DIM);
  ((float4*)xs)[lane] = xr[lane];
  ((float4*)xs)[lane + 64] = xr[lane + 64];
  __syncthreads();
  if (lane < E_NUM) {
    const float* w = gw + (size_t)lane * H_DIM;
    float acc = 0.f;
    #pragma unroll 8
    for (int h = 0; h < H_DIM; h++) acc += xs[h] * w[h];
    lg[lane] = acc;
  }
  __syncthreads();
  if (lane == 0) {
    float mx = lg[0];
    #pragma unroll
    for (int e = 1; e < E_NUM; e++) mx = fmaxf(mx, lg[e]);
    float sc[E_NUM];
    float sum = 0.f;
    #pragma unroll
    for (int e = 0; e < E_NUM; e++) { sc[e] = expf(lg[e] - mx); sum += sc[e]; }
    float inv = 1.f / sum;
    float m1 = -1.f, m2 = -1.f; int i1 = 0, i2 = 0;
    #pragma unroll
    for (int e = 0; e < E_NUM; e++) {
      float s = sc[e] * inv;
      if (s > m1)      { m2 = m1; i2 = i1; m1 = s; i1 = e; }
      else if (s > m2) { m2 = s; i2 = e; }
    }
    topk_idx[t * 2] = i1; topk_idx[t * 2 + 1] = i2;
    topk_w[t * 2] = m1;  topk_w[t * 2 + 1] = m2;
    atomicAdd(&counts[i1], 1);
    atomicAdd(&counts[i2], 1);
  }
}

// ---------------- 2) exclusive scan over 16 counts ----------------
__global__ void offsets_kernel(const int* __restrict__ counts,
                               int* __restrict__ offsets, int* __restrict__ cursor)
{
  if (threadIdx.x == 0) {
    int acc = 0;
    #pragma unroll
    for (int e = 0; e < E_NUM; e++) { offsets[e] = acc; acc += counts[e]; }
    offsets[E_NUM] = acc;
  }
  if (threadIdx.x < E_NUM) cursor[threadIdx.x] = 0;
}

// ---------------- 3) scatter tokens into per-expert lists ----------------
__global__ __launch_bounds__(256) void scatter_kernel(
    const int* __restrict__ topk_idx, const float* __restrict__ topk_w,
    const int* __restrict__ offsets, int* __restrict__ cursor,
    int* __restrict__ row_token, float* __restrict__ row_w)
{
  int t = blockIdx.x * 256 + threadIdx.x;
  if (t >= T_TOK) return;
  #pragma unroll
  for (int k = 0; k < TOPK; k++) {
    int e = topk_idx[t * 2 + k];
    int pos = atomicAdd(&cursor[e], 1);
    int row = offsets[e] + pos;
    row_token[row] = t;
    row_w[row] = topk_w[t * 2 + k];
  }
}

// ---------------- 4) grouped GU GEMM (bf16 in): inter = silu(X*Wg^T).*(X*Wu^T) ----
// BM=128 rows, BN=64 cols (of both g and u), BK=32, 256 thr (4 waves 2x2).
// m97-style: global_load_lds width-16 staging, 2 barriers / K-step.
// LDS swizzle: slot u' of row holds k-group u'^((row>>1)&3) (source pre-swizzled).
__global__ __launch_bounds__(256) void gu2_kernel(
    const ushort_t* __restrict__ xb,                       // [T,512] bf16
    const ushort_t* __restrict__ wg_all,
    const ushort_t* __restrict__ wu_all,                   // [E,Idim,512]
    ushort_t* __restrict__ inter,
    const int* __restrict__ row_token,                     // null -> identity rows
    const int* __restrict__ counts,                        // null -> cnt=total_rows
    const int* __restrict__ offsets,                       // null -> base=0
    int Idim, int total_rows, int maxrt)
{
  int e  = blockIdx.x / maxrt;
  int rt = blockIdx.x % maxrt;
  int cnt = counts ? counts[e] : total_rows;
  int n0 = rt * 128;
  if (n0 >= cnt) return;
  int base = offsets ? offsets[e] : 0;
  int c0 = blockIdx.y * 64;
  const ushort_t* wg = wg_all + (size_t)e * Idim * H_DIM;
  const ushort_t* wu = wu_all + (size_t)e * Idim * H_DIM;

  __shared__ __align__(16) ushort_t As[128 * 32];   // 8 KB
  __shared__ __align__(16) ushort_t Bg[64 * 32];    // 4 KB
  __shared__ __align__(16) ushort_t Bu[64 * 32];    // 4 KB

  int tid = threadIdx.x;
  int wid = tid >> 6, lane = tid & 63;

  // --- staging addresses ---
  int r0 = wid * 16 + (lane >> 2);          // A rows 0..63 (issue 0)
  int r1 = 64 + r0;                          // A rows 64..127 (issue 1)
  int rb = r0;                               // B rows 0..63
  int rr0 = n0 + r0; if (rr0 >= cnt) rr0 = cnt - 1;
  int rr1 = n0 + r1; if (rr1 >= cnt) rr1 = cnt - 1;
  int tok0 = row_token ? row_token[base + rr0] : (base + rr0);
  int tok1 = row_token ? row_token[base + rr1] : (base + rr1);
  int k8_0 = (lane & 3) ^ ((r0 >> 1) & 3);
  int k8_1 = (lane & 3) ^ ((r1 >> 1) & 3);
  int k8_b = (lane & 3) ^ ((rb >> 1) & 3);
  const ushort_t* a0src = xb + (size_t)tok0 * H_DIM + k8_0 * 8;
  const ushort_t* a1src = xb + (size_t)tok1 * H_DIM + k8_1 * 8;
  const ushort_t* bgsrc = wg + (size_t)(c0 + rb) * H_DIM + k8_b * 8;
  const ushort_t* busrc = wu + (size_t)(c0 + rb) * H_DIM + k8_b * 8;
  ushort_t* a0dst = As + wid * 512;          // rows wid*16..+15
  ushort_t* a1dst = As + 2048 + wid * 512;   // rows 64+wid*16..
  ushort_t* bgdst = Bg + wid * 512;
  ushort_t* budst = Bu + wid * 512;

  // --- fragment read offsets ---
  int wr = (wid >> 1) * 64;                  // 0 / 64
  int wc = (wid & 1) * 32;                   // 0 / 32
  int fr = lane & 15, g = lane >> 4;

  f32x4 accg[4][2] = {};
  f32x4 accu[4][2] = {};

  int aoff[4], boff[2];
  #pragma unroll
  for (int m = 0; m < 4; m++) {
    int row = wr + m * 16 + fr;
    aoff[m] = row * 32 + ((g ^ ((row >> 1) & 3)) << 3);
  }
  #pragma unroll
  for (int n = 0; n < 2; n++) {
    int row = wc + n * 16 + fr;
    boff[n] = row * 32 + ((g ^ ((row >> 1) & 3)) << 3);
  }

  for (int k0 = 0; k0 < H_DIM; k0 += 32) {
    gload_lds16(a0src + k0, a0dst);
    gload_lds16(a1src + k0, a1dst);
    gload_lds16(bgsrc + k0, bgdst);
    gload_lds16(busrc + k0, budst);
    __syncthreads();

    bf16x8 af[4], bgf[2], buf2[2];
    #pragma unroll
    for (int m = 0; m < 4; m++) af[m] = *(const bf16x8*)&As[aoff[m]];
    #pragma unroll
    for (int n = 0; n < 2; n++) {
      bgf[n]  = *(const bf16x8*)&Bg[boff[n]];
      buf2[n] = *(const bf16x8*)&Bu[boff[n]];
    }
    #pragma unroll
    for (int m = 0; m < 4; m++) {
      #pragma unroll
      for (int n = 0; n < 2; n++) {
        accg[m][n] = __builtin_amdgcn_mfma_f32_16x16x32_bf16(af[m], bgf[n],  accg[m][n], 0, 0, 0);
        accu[m][n] = __builtin_amdgcn_mfma_f32_16x16x32_bf16(af[m], buf2[n], accu[m][n], 0, 0, 0);
      }
    }
    __syncthreads();
  }

  // epilogue: silu(g)*u -> bf16 inter
  #pragma unroll
  for (int m = 0; m < 4; m++) {
    #pragma unroll
    for (int j = 0; j < 4; j++) {
      int r = wr + m * 16 + g * 4 + j;
      if (n0 + r < cnt) {
        size_t orow = (size_t)(base + n0 + r) * Idim;
        #pragma unroll
        for (int n = 0; n < 2; n++) {
          float gg = accg[m][n][j], uu = accu[m][n][j];
          float s = (gg / (1.f + expf(-gg))) * uu;
          inter[orow + c0 + wc + n * 16 + fr] = f2bf(s);
        }
      }
    }
  }
}

// ---------------- 5) down GEMM (bf16 in): out (+)= (inter * Wd^T) [* weight] ------
// BM=64, BN=64, BK=32, 256 thr (4 waves 2x2, 32x32 each).
__global__ __launch_bounds__(256) void down2_kernel(
    const ushort_t* __restrict__ inter,                    // [rows,Kdim] bf16
    const ushort_t* __restrict__ wd_all,                   // [E,H,Kdim] bf16
    float* __restrict__ outp,
    const int* __restrict__ row_token,                     // null -> identity rows
    const float* __restrict__ row_w,                       // null -> store path
    const int* __restrict__ counts, const int* __restrict__ offsets,
    int Kdim, int total_rows, int maxrt)
{
  int e  = blockIdx.x / maxrt;
  int rt = blockIdx.x % maxrt;
  int cnt = counts ? counts[e] : total_rows;
  int n0 = rt * 64;
  if (n0 >= cnt) return;
  int base = offsets ? offsets[e] : 0;
  int c0 = blockIdx.y * 64;
  const ushort_t* wd = wd_all + (size_t)e * H_DIM * Kdim;

  __shared__ __align__(16) ushort_t As[64 * 32];   // 4 KB
  __shared__ __align__(16) ushort_t Bs[64 * 32];   // 4 KB
  __shared__ int   toks[64];
  __shared__ float rws[64];

  int tid = threadIdx.x;
  if (tid < 64) {
    int r = n0 + tid;
    if (r < cnt) {
      int row = base + r;
      toks[tid] = row_token ? row_token[row] : row;
      rws[tid]  = row_w ? row_w[row] : 1.f;
    } else { toks[tid] = 0; rws[tid] = 0.f; }
  }

  int wid = tid >> 6, lane = tid & 63;
  int rs = wid * 16 + (lane >> 2);          // staged row 0..63
  int k8 = (lane & 3) ^ ((rs >> 1) & 3);
  // A rows are contiguous grouped rows (may read past cnt into adjacent ws -> safe, guarded stores)
  const ushort_t* asrc = inter + (size_t)(base + n0 + rs) * Kdim + k8 * 8;
  const ushort_t* bsrc = wd + (size_t)(c0 + rs) * Kdim + k8 * 8;
  ushort_t* adst = As + wid * 512;
  ushort_t* bdst = Bs + wid * 512;

  int wr = (wid >> 1) * 32;
  int wc = (wid & 1) * 32;
  int fr = lane & 15, g = lane >> 4;

  int aoff[2], boff[2];
  #pragma unroll
  for (int m = 0; m < 2; m++) {
    int row = wr + m * 16 + fr;
    aoff[m] = row * 32 + ((g ^ ((row >> 1) & 3)) << 3);
  }
  #pragma unroll
  for (int n = 0; n < 2; n++) {
    int row = wc + n * 16 + fr;
    boff[n] = row * 32 + ((g ^ ((row >> 1) & 3)) << 3);
  }

  f32x4 acc[2][2] = {};
  __syncthreads();   // toks/rws visible

  for (int k0 = 0; k0 < Kdim; k0 += 32) {
    gload_lds16(asrc + k0, adst);
    gload_lds16(bsrc + k0, bdst);
    __syncthreads();
    bf16x8 af[2], bf[2];
    #pragma unroll
    for (int m = 0; m < 2; m++) af[m] = *(const bf16x8*)&As[aoff[m]];
    #pragma unroll
    for (int n = 0; n < 2; n++) bf[n] = *(const bf16x8*)&Bs[boff[n]];
    #pragma unroll
    for (int m = 0; m < 2; m++)
      #pragma unroll
      for (int n = 0; n < 2; n++)
        acc[m][n] = __builtin_amdgcn_mfma_f32_16x16x32_bf16(af[m], bf[n], acc[m][n], 0, 0, 0);
    __syncthreads();
  }

  #pragma unroll
  for (int m = 0; m < 2; m++) {
    #pragma unroll
    for (int j = 0; j < 4; j++) {
      int r = wr + m * 16 + g * 4 + j;
      if (n0 + r < cnt) {
        int tk = toks[r];
        float rw = rws[r];
        #pragma unroll
        for (int n = 0; n < 2; n++) {
          int col = c0 + wc + n * 16 + fr;
          float v = acc[m][n][j];
          if (row_w) atomicAdd(&outp[(size_t)tk * H_DIM + col], v * rw);
          else       outp[(size_t)tk * H_DIM + col] = v;
        }
      }
    }
  }
}

// ---------------- launch ----------------
extern "C" void kernel_launch(void* const* d_in, const int* in_sizes, int n_in,
                              void* d_out, int out_size, void* d_ws, size_t ws_size,
                              hipStream_t stream) {
  const float* x       = (const float*)d_in[0];
  const float* gate_w  = (const float*)d_in[1];
  const float* w_gate  = (const float*)d_in[2];
  const float* w_up    = (const float*)d_in[3];
  const float* w_down  = (const float*)d_in[4];
  const float* sw_gate = (const float*)d_in[5];
  const float* sw_up   = (const float*)d_in[6];
  const float* sw_down = (const float*)d_in[7];
  float* out = (float*)d_out;

  char* ws = (char*)d_ws;
  int*   counts    = (int*)ws;                    // 16 ints
  int*   cursor    = (int*)(ws + 64);             // 16 ints
  int*   offsets   = (int*)(ws + 128);            // 17 ints
  int*   topk_idx  = (int*)(ws + 256);            // 4096 ints
  float* topk_w    = (float*)(ws + 16640);        // 4096 f32
  int*   row_token = (int*)(ws + 33024);          // 4096 ints
  float* row_w     = (float*)(ws + 49408);        // 4096 f32
  size_t off = 65792;
  ushort_t* xb   = (ushort_t*)(ws + off); off += (size_t)T_TOK * H_DIM * 2;        // 2 MiB
  ushort_t* wgb  = (ushort_t*)(ws + off); off += (size_t)E_NUM * I_DIM * H_DIM * 2; // 32 MiB
  ushort_t* wub  = (ushort_t*)(ws + off); off += (size_t)E_NUM * I_DIM * H_DIM * 2; // 32 MiB
  ushort_t* wdb  = (ushort_t*)(ws + off); off += (size_t)E_NUM * H_DIM * I_DIM * 2; // 32 MiB
  ushort_t* swgb = (ushort_t*)(ws + off); off += (size_t)IS_DIM * H_DIM * 2;       // 1 MiB
  ushort_t* swub = (ushort_t*)(ws + off); off += (size_t)IS_DIM * H_DIM * 2;       // 1 MiB
  ushort_t* swdb = (ushort_t*)(ws + off); off += (size_t)H_DIM * IS_DIM * 2;       // 1 MiB
  ushort_t* inter_r = (ushort_t*)(ws + off); off += (size_t)NROWS * I_DIM * 2;     // 16 MiB
  ushort_t* inter_s = (ushort_t*)(ws + off); off += (size_t)T_TOK * IS_DIM * 2;    // 4 MiB

  hipMemsetAsync(counts, 0, 64, stream);
  gate_kernel<<<T_TOK, 64, 0, stream>>>(x, gate_w, topk_idx, topk_w, counts);
  offsets_kernel<<<1, 64, 0, stream>>>(counts, offsets, cursor);
  scatter_kernel<<<(T_TOK + 255) / 256, 256, 0, stream>>>(topk_idx, topk_w, offsets, cursor,
                                                          row_token, row_w);
  // fp32 -> bf16 conversions
  conv_kernel<<<512, 256, 0, stream>>>(x, xb, T_TOK * H_DIM / 8);
  conv_kernel<<<4096, 256, 0, stream>>>(w_gate, wgb, E_NUM * I_DIM * H_DIM / 8);
  conv_kernel<<<4096, 256, 0, stream>>>(w_up, wub, E_NUM * I_DIM * H_DIM / 8);
  conv_kernel<<<4096, 256, 0, stream>>>(w_down, wdb, E_NUM * H_DIM * I_DIM / 8);
  conv_kernel<<<256, 256, 0, stream>>>(sw_gate, swgb, IS_DIM * H_DIM / 8);
  conv_kernel<<<256, 256, 0, stream>>>(sw_up, swub, IS_DIM * H_DIM / 8);
  conv_kernel<<<256, 256, 0, stream>>>(sw_down, swdb, H_DIM * IS_DIM / 8);

  // routed GU: grid (E * maxrt, Idim/64), maxrt = 2048/128
  gu2_kernel<<<dim3(E_NUM * 16, I_DIM / 64), 256, 0, stream>>>(
      xb, wgb, wub, inter_r, row_token, counts, offsets, I_DIM, NROWS, 16);
  // shared GU: dense 2048 rows, Idim = IS
  gu2_kernel<<<dim3(16, IS_DIM / 64), 256, 0, stream>>>(
      xb, swgb, swub, inter_s, nullptr, nullptr, nullptr, IS_DIM, T_TOK, 16);
  // shared down first (plain stores initialize out fully)
  down2_kernel<<<dim3(32, H_DIM / 64), 256, 0, stream>>>(
      inter_s, swdb, out, nullptr, nullptr, nullptr, nullptr, IS_DIM, T_TOK, 32);
  // routed down: weighted atomic accumulation into out
  down2_kernel<<<dim3(E_NUM * 32, H_DIM / 64), 256, 0, stream>>>(
      inter_r, wdb, out, row_token, row_w, counts, offsets, I_DIM, NROWS, 32);
}